// Round 18
// baseline (190.882 us; speedup 1.0000x reference)
//
#include <hip/hip_runtime.h>
#include <hip/hip_fp16.h>
#include <cmath>

// Problem dims: B=4, C=64, H=W=256, k=3
namespace {
constexpr int Bn = 4, Cn = 64, Hn = 256, Wn = 256;
constexpr int HWn = Hn * Wn;              // 65536
// ws layout, BYTE offsets:
constexpr size_t OFF_PRE_LOW  = 0;          // a_low pre, NHWC f16, 33554432 B
constexpr size_t OFF_PRE_HIGH = 33554432;   // a_high pre, NHWC f16 (epilogue-only reader)
constexpr size_t OFF_OM_COL   = 67108864;   // om col (B,9,H,W) f16, 4718592 B
constexpr size_t OFF_OM_ROW   = 71827456;   // om row f16
constexpr size_t OFF_WOF16    = 85999616;   // offset-conv weights c-paired half2: [md][c2][k][9]
constexpr size_t OFF_WPACK    = 86013440;   // deform MFMA A-frag f16, 2 modes * 12288 halves
constexpr size_t OFF_WPRE     = 86062592;   // composed W2*W1 MFMA A-frag f16, 4096 halves
constexpr size_t OFF_BEFF     = 86070784;   // composed bias, 64 f32
// total ~86.1 MB. d_out is not used as scratch anymore.

// k_dfuse LDS layout (bytes) — below 32KB for 5 blocks/CU:
constexpr int L_WIN  = 0;       // window: 180 px (5 rows x 36 cols) x 144 B
constexpr int L_MOFF = 25920;   // ushort4[192] window byte-offsets per (m,tap,p)
constexpr int L_MW   = 27456;   // __half[192][4] bilinear weights
constexpr int L_CRD  = 28992;   // uchar4[192] clamped corner coords (y0,x0,y1,x1)
constexpr int L_MSK  = 29760;   // uint[192] OOW corner mask (slow path only)
constexpr int L_ZL   = 30528;   // 144 B zero line
constexpr int L_TOT  = 30672;
// EX overlay f32[2][32][68] = 17408 B aliases window after gather barrier
}

typedef _Float16 f16x8 __attribute__((ext_vector_type(8)));
typedef float f32x4 __attribute__((ext_vector_type(4)));

__device__ __forceinline__ float sigm(float x) { return 1.f / (1.f + __expf(-x)); }
__device__ __forceinline__ __half2 bc2(unsigned u) { return __builtin_bit_cast(__half2, u); }
__device__ __forceinline__ unsigned u32of(__half2 h) { return __builtin_bit_cast(unsigned, h); }

// ---------------- weight repack + W2*W1 composition (tiny) ----------------
__global__ void k_repack(const float* __restrict__ pw1, const float* __restrict__ pw2,
                         const float* __restrict__ b1,  const float* __restrict__ b2,
                         const float* __restrict__ owc, const float* __restrict__ owr,
                         const float* __restrict__ wc,  const float* __restrict__ wr,
                         char* __restrict__ ws8)
{
    unsigned* Wo2  = (unsigned*)(ws8 + OFF_WOF16);
    __half*   Wp   = (__half*)(ws8 + OFF_WPACK);
    __half*   Wpre = (__half*)(ws8 + OFF_WPRE);
    float*    Beff = (float*)(ws8 + OFF_BEFF);
    int t = blockIdx.x * 256 + threadIdx.x;
    int stride = gridDim.x * 256;
    // offset-conv weights channel-paired half2: Wo2[md*864 + c2*27 + k*9 + d] =
    //   (w[d][2c2][k], w[d][2c2+1][k])
    for (int i = t; i < 1728; i += stride) {
        int md = i >= 864;
        int rem = i - md * 864;
        int c2 = rem / 27, kd = rem - c2 * 27;
        int k = kd / 9, d = kd - k * 9;
        const float* src = md ? owr : owc;
        float lo = src[d * 192 + (2 * c2) * 3 + k];
        float hi = src[d * 192 + (2 * c2 + 1) * 3 + k];
        Wo2[i] = u32of(__floats2half2_rn(lo, hi));
    }
    // deform MFMA A-frag pack (f16)
    for (int i = t; i < 24576; i += stride) {
        int m = i >= 12288;
        int rem = i - m * 12288;
        int e = rem & 7, l = (rem >> 3) & 63, os = (rem >> 9) & 3, s = rem >> 11;
        int kk = 32 * s + (l >> 4) * 8 + e;
        int o = os * 16 + (l & 15);
        int c = kk & 63, tap = kk >> 6;
        const float* src = m ? wr : wc;
        Wp[i] = __float2half(src[o * 192 + c * 3 + tap]);
    }
    // composed preprocess weight + bias
    for (int i = t; i < 4096; i += stride) {
        int e = i & 7, l = (i >> 3) & 63, os = (i >> 9) & 3, s = i >> 11;
        int o = os * 16 + (l & 15);
        int c = 32 * s + (l >> 4) * 8 + e;
        float a = 0.f;
        for (int j = 0; j < 32; j++) a += pw2[o * 32 + j] * pw1[j * 64 + c];
        Wpre[i] = __float2half(a);
    }
    for (int i = t; i < 64; i += stride) {
        float a = b2[i];
        for (int j = 0; j < 32; j++) a += pw2[i * 32 + j] * b1[j];
        Beff[i] = a;
    }
}

// ---------------- preprocess via composed MFMA GEMM (NHWC-only outputs) ----------------
__global__ __launch_bounds__(256) void k_pre(const float* __restrict__ alow,
                                             const float* __restrict__ ahigh,
                                             char* __restrict__ ws8)
{
    __shared__ __align__(16) char XSb[32768];   // XS[px 256][c 64] f16, swizzled
    int bid = blockIdx.x;                // [0, 2048)
    int tensor = bid >> 10;
    int r = bid & 1023;                  // b*256 + h
    const float* __restrict__ x = (tensor ? ahigh : alow) + (size_t)r * Wn
                                  + (size_t)(r >> 8) * (Cn - 1) * HWn;
    // note: base = tensor + b*C*HW + h*W  (r*W + b*(C-1)*HW)
    int tid = threadIdx.x;

#pragma unroll
    for (int it = 0; it < 4; it++) {
        int job = tid + it * 256;
        int c4 = job >> 6, pxg = job & 63;
        int c0 = c4 * 4;
        float4 f0 = *reinterpret_cast<const float4*>(x + (size_t)(c0 + 0) * HWn + pxg * 4);
        float4 f1 = *reinterpret_cast<const float4*>(x + (size_t)(c0 + 1) * HWn + pxg * 4);
        float4 f2 = *reinterpret_cast<const float4*>(x + (size_t)(c0 + 2) * HWn + pxg * 4);
        float4 f3 = *reinterpret_cast<const float4*>(x + (size_t)(c0 + 3) * HWn + pxg * 4);
        const float* p0 = reinterpret_cast<const float*>(&f0);
        const float* p1 = reinterpret_cast<const float*>(&f1);
        const float* p2 = reinterpret_cast<const float*>(&f2);
        const float* p3 = reinterpret_cast<const float*>(&f3);
        int u = c4 >> 1, hf = c4 & 1;
#pragma unroll
        for (int i = 0; i < 4; i++) {
            int px = pxg * 4 + i;
            uint2 v;
            v.x = u32of(__float22half2_rn({p0[i], p1[i]}));
            v.y = u32of(__float22half2_rn({p2[i], p3[i]}));
            *reinterpret_cast<uint2*>(XSb + px * 128 + ((u ^ (px & 7)) * 16) + hf * 8) = v;
        }
    }
    __syncthreads();

    int wv = tid >> 6, lane = tid & 63;
    int kq = lane >> 4, n = lane & 15;
    const f16x8* __restrict__ Wf = (const f16x8*)(ws8 + OFF_WPRE);
    const float* __restrict__ beff = (const float*)(ws8 + OFF_BEFF);
    f16x8 af[8];
#pragma unroll
    for (int i = 0; i < 8; i++) af[i] = Wf[i * 64 + lane];
    f32x4 zero = {0.f, 0.f, 0.f, 0.f};
    f32x4 acc[16];
#pragma unroll
    for (int i = 0; i < 16; i++) acc[i] = zero;
#pragma unroll
    for (int s = 0; s < 2; s++) {
#pragma unroll
        for (int pt = 0; pt < 4; pt++) {
            int px = wv * 64 + pt * 16 + n;
            int u = (4 * s + kq) ^ (px & 7);
            f16x8 bf = *reinterpret_cast<const f16x8*>(XSb + px * 128 + u * 16);
#pragma unroll
            for (int os = 0; os < 4; os++)
                acc[os * 4 + pt] = __builtin_amdgcn_mfma_f32_16x16x32_f16(
                    af[s * 4 + os], bf, acc[os * 4 + pt], 0, 0, 0);
        }
    }
#pragma unroll
    for (int os = 0; os < 4; os++) {
        float4 bq = *reinterpret_cast<const float4*>(beff + os * 16 + kq * 4);
        const float* bqp = reinterpret_cast<const float*>(&bq);
#pragma unroll
        for (int pt = 0; pt < 4; pt++)
#pragma unroll
            for (int rg = 0; rg < 4; rg++) acc[os * 4 + pt][rg] += bqp[rg];
    }

    __half* __restrict__ outp = (__half*)(ws8 + (tensor ? OFF_PRE_HIGH : OFF_PRE_LOW))
                                + (size_t)r * 16384;
#pragma unroll
    for (int os = 0; os < 4; os++)
#pragma unroll
        for (int pt = 0; pt < 4; pt++) {
            int px = wv * 64 + pt * 16 + n;
            uint2 v;
            v.x = u32of(__float22half2_rn({acc[os * 4 + pt][0], acc[os * 4 + pt][1]}));
            v.y = u32of(__float22half2_rn({acc[os * 4 + pt][2], acc[os * 4 + pt][3]}));
            *reinterpret_cast<uint2*>(outp + (size_t)px * 64 + os * 16 + kq * 4) = v;
        }
}

// ---------------- offset convs from NHWC: thread = (pixel, mode) ----------------
// 3 neighbor pixel-vectors (128B each) via 24 uint4 loads; c-paired half2 MACs;
// weights wave-uniform (s_load). 2048 blocks.
__global__ __launch_bounds__(256) void k_om2(const float* __restrict__ ocb,
                                             const float* __restrict__ orb,
                                             char* __restrict__ ws8)
{
    int bid = blockIdx.x;                 // [0, 2048)
    int md = bid & 1;
    int r = bid >> 1;                     // b*256 + h
    int h = r & 255;
    int w = threadIdx.x;
    const __half* __restrict__ A = (const __half*)(ws8 + OFF_PRE_LOW);
    const uint4* __restrict__ pc = reinterpret_cast<const uint4*>(A + ((size_t)r * 256 + w) * 64);
    bool v0, v2;
    int o0, o2;
    if (md == 0) { v0 = (h > 0);  v2 = (h < Hn - 1); o0 = -2048; o2 = 2048; }
    else         { v0 = (w > 0);  v2 = (w < Wn - 1); o0 = -8;    o2 = 8; }
    const uint4* p0 = pc + (v0 ? o0 : 0);
    const uint4* p2 = pc + (v2 ? o2 : 0);
    const unsigned* __restrict__ Wt = (const unsigned*)(ws8 + OFF_WOF16) + md * 864;

    const __half2 z = __float2half2_rn(0.f);
    uint4 z4 = {0u, 0u, 0u, 0u};
    __half2 acc[9];
#pragma unroll
    for (int d = 0; d < 9; d++) acc[d] = z;

#pragma unroll 2
    for (int u = 0; u < 8; u++) {
        uint4 x0 = p0[u]; if (!v0) x0 = z4;
        uint4 x1 = pc[u];
        uint4 x2 = p2[u]; if (!v2) x2 = z4;
        const unsigned* xp0 = reinterpret_cast<const unsigned*>(&x0);
        const unsigned* xp1 = reinterpret_cast<const unsigned*>(&x1);
        const unsigned* xp2 = reinterpret_cast<const unsigned*>(&x2);
#pragma unroll
        for (int j = 0; j < 4; j++) {
            int c2 = u * 4 + j;
            const unsigned* wb = Wt + c2 * 27;
            __half2 a0 = bc2(xp0[j]), a1 = bc2(xp1[j]), a2 = bc2(xp2[j]);
#pragma unroll
            for (int d = 0; d < 9; d++)
                acc[d] = __hfma2(bc2(wb[d]), a0,
                          __hfma2(bc2(wb[9 + d]), a1,
                           __hfma2(bc2(wb[18 + d]), a2, acc[d])));
        }
    }

    const float* __restrict__ bias = md ? orb : ocb;
    __half* __restrict__ om = (__half*)(ws8 + (md ? OFF_OM_ROW : OFF_OM_COL));
    size_t ob = ((size_t)(r >> 8) * 9) * HWn + (size_t)h * Wn + w;
#pragma unroll
    for (int d = 0; d < 9; d++) {
        float v = __low2float(acc[d]) + __high2float(acc[d]) + bias[d];
        om[ob + (size_t)d * HWn] = __float2half(v);
    }
}

// ---------------- fused deformable conv: LDS-window gather, 5 blocks/CU ----------------
__global__ __launch_bounds__(256, 5) void k_dfuse(const float* __restrict__ bc,
                                                  const float* __restrict__ br,
                                                  float* __restrict__ out,
                                                  char* __restrict__ ws8)
{
    __shared__ __align__(16) char smem8[L_TOT];

    const __half* __restrict__ A16 = (const __half*)(ws8 + OFF_PRE_LOW);

    int bid = blockIdx.x;                 // 8192 blocks, 8192 % 8 == 0 (bijective)
    int blk = (bid & 7) * 1024 + (bid >> 3);
    int wt = blk & 7, bh = blk >> 3, h = bh & 255, b = bh >> 8;
    int w0 = wt * 32;
    int tid = threadIdx.x;
    int pbase = b * HWn;

    // ---- stage 5x36 window (all threads; coalesced 16B chunks) ----
    {
        int ylo = h - 2, xlo = w0 - 2;
#pragma unroll
        for (int i = 0; i < 6; i++) {
            int idx = tid + i * 256;
            if (idx < 1440) {
                int pixw = idx >> 3, ch = idx & 7;
                int r = pixw / 36;
                int xi = pixw - r * 36;
                int y = min(max(ylo + r, 0), Hn - 1);
                int x = min(max(xlo + xi, 0), Wn - 1);
                size_t src = ((size_t)pbase + y * Wn + x) * 64 + ch * 8;
                *reinterpret_cast<uint4*>(smem8 + L_WIN + pixw * 144 + ch * 16) =
                    *reinterpret_cast<const uint4*>(A16 + src);
            }
        }
    }
    if (tid >= 192 && tid < 201) {
        uint4 z4 = {0u, 0u, 0u, 0u};
        *reinterpret_cast<uint4*>(smem8 + L_ZL + (tid - 192) * 16) = z4;
    }

    // ---- decode (threads 0..191) ----
    int myMsk = 0;
    if (tid < 192) {
        int m = tid >= 96 ? 1 : 0;
        int jj = tid - m * 96;            // tap*32 + p
        int p = jj & 31, tap = jj >> 5;
        int w = w0 + p;
        const __half* __restrict__ om = (const __half*)(ws8 + (m ? OFF_OM_ROW : OFF_OM_COL));
        size_t ob = ((size_t)b * 9 * Hn + h) * Wn + w;
        float dy = __half2float(om[ob + (size_t)tap * HWn]);
        float dx = __half2float(om[ob + (size_t)(3 + tap) * HWn]);
        float mm = __half2float(om[ob + (size_t)(6 + tap) * HWn]);
        float mask = sigm(mm);
        float py = dy + (float)h + (m ? 0.f : (float)(tap - 1));
        float px = dx + (float)w + (m ? (float)(tap - 1) : 0.f);
        float fy = floorf(py), fx = floorf(px);
        float ty = py - fy, tx = px - fx;
        int y0 = (int)fy, x0 = (int)fx;
        int y1 = y0 + 1, x1 = x0 + 1;
        float vy0 = ((unsigned)y0 < (unsigned)Hn) ? 1.f : 0.f;
        float vy1 = ((unsigned)y1 < (unsigned)Hn) ? 1.f : 0.f;
        float vx0 = ((unsigned)x0 < (unsigned)Wn) ? 1.f : 0.f;
        float vx1 = ((unsigned)x1 < (unsigned)Wn) ? 1.f : 0.f;
        int y0c = min(max(y0, 0), Hn - 1), y1c = min(max(y1, 0), Hn - 1);
        int x0c = min(max(x0, 0), Wn - 1), x1c = min(max(x1, 0), Wn - 1);
        float ry = 1.f - ty, rx = 1.f - tx;
        float w00 = ry * rx * mask * vy0 * vx0;
        float w01 = ry * tx * mask * vy0 * vx1;
        float w10 = ty * rx * mask * vy1 * vx0;
        float w11 = ty * tx * mask * vy1 * vx1;
        int yw0 = y0c - (h - 2), yw1 = y1c - (h - 2);
        int xw0 = x0c - (w0 - 2), xw1 = x1c - (w0 - 2);
        bool i00 = ((unsigned)yw0 < 5u) && ((unsigned)xw0 < 36u);
        bool i01 = ((unsigned)yw0 < 5u) && ((unsigned)xw1 < 36u);
        bool i10 = ((unsigned)yw1 < 5u) && ((unsigned)xw0 < 36u);
        bool i11 = ((unsigned)yw1 < 5u) && ((unsigned)xw1 < 36u);
        ushort4 offs;
        offs.x = i00 ? (ushort)((yw0 * 36 + xw0) * 144) : (ushort)L_ZL;
        offs.y = i01 ? (ushort)((yw0 * 36 + xw1) * 144) : (ushort)L_ZL;
        offs.z = i10 ? (ushort)((yw1 * 36 + xw0) * 144) : (ushort)L_ZL;
        offs.w = i11 ? (ushort)((yw1 * 36 + xw1) * 144) : (ushort)L_ZL;
        *reinterpret_cast<ushort4*>(smem8 + L_MOFF + tid * 8) = offs;
        __half* mw = reinterpret_cast<__half*>(smem8 + L_MW + tid * 8);
        mw[0] = __float2half(w00); mw[1] = __float2half(w01);
        mw[2] = __float2half(w10); mw[3] = __float2half(w11);
        uchar4 cr = { (unsigned char)y0c, (unsigned char)x0c,
                      (unsigned char)y1c, (unsigned char)x1c };
        *reinterpret_cast<uchar4*>(smem8 + L_CRD + tid * 4) = cr;
        myMsk = (i00 ? 0 : 1) | (i01 ? 0 : 2) | (i10 ? 0 : 4) | (i11 ? 0 : 8);
        *reinterpret_cast<unsigned*>(smem8 + L_MSK + tid * 4) = (unsigned)myMsk;
    }
    int anyOOW = __syncthreads_or(myMsk);

    // ---- gather (from LDS) + GEMM ----
    int wv = tid >> 6, lane = tid & 63;
    int m = wv >> 1, pg = wv & 1;
    int n = lane & 15, kq = lane >> 4;
    int p = pg * 16 + n;
    const f16x8* __restrict__ Wf = (const f16x8*)(ws8 + OFF_WPACK + (size_t)m * 24576);

    ushort4 offs[3];
    __half2 wh[3][4];
#pragma unroll
    for (int t3 = 0; t3 < 3; t3++) {
        int idx = m * 96 + t3 * 32 + p;
        offs[t3] = *reinterpret_cast<const ushort4*>(smem8 + L_MOFF + idx * 8);
        uint2 wr_ = *reinterpret_cast<const uint2*>(smem8 + L_MW + idx * 8);
        __half2 wa = bc2(wr_.x), wb = bc2(wr_.y);
        wh[t3][0] = __half2half2(__low2half(wa));
        wh[t3][1] = __half2half2(__high2half(wa));
        wh[t3][2] = __half2half2(__low2half(wb));
        wh[t3][3] = __half2half2(__high2half(wb));
    }

    f32x4 zero = {0.f, 0.f, 0.f, 0.f};
    f32x4 acc[4] = {zero, zero, zero, zero};

#define GBLEND(T, CO, A0, A1, A2, A3)                                            \
    {                                                                            \
        uint4 u0 = *reinterpret_cast<const uint4*>(smem8 + (int)offs[T].x + (CO)); \
        uint4 u1 = *reinterpret_cast<const uint4*>(smem8 + (int)offs[T].y + (CO)); \
        uint4 u2 = *reinterpret_cast<const uint4*>(smem8 + (int)offs[T].z + (CO)); \
        uint4 u3 = *reinterpret_cast<const uint4*>(smem8 + (int)offs[T].w + (CO)); \
        A0 = __hmul2(bc2(u0.x), wh[T][0]); A1 = __hmul2(bc2(u0.y), wh[T][0]);    \
        A2 = __hmul2(bc2(u0.z), wh[T][0]); A3 = __hmul2(bc2(u0.w), wh[T][0]);    \
        A0 = __hfma2(bc2(u1.x), wh[T][1], A0); A1 = __hfma2(bc2(u1.y), wh[T][1], A1); \
        A2 = __hfma2(bc2(u1.z), wh[T][1], A2); A3 = __hfma2(bc2(u1.w), wh[T][1], A3); \
        A0 = __hfma2(bc2(u2.x), wh[T][2], A0); A1 = __hfma2(bc2(u2.y), wh[T][2], A1); \
        A2 = __hfma2(bc2(u2.z), wh[T][2], A2); A3 = __hfma2(bc2(u2.w), wh[T][2], A3); \
        A0 = __hfma2(bc2(u3.x), wh[T][3], A0); A1 = __hfma2(bc2(u3.y), wh[T][3], A1); \
        A2 = __hfma2(bc2(u3.z), wh[T][3], A2); A3 = __hfma2(bc2(u3.w), wh[T][3], A3); \
    }

    if (!anyOOW) {
#pragma unroll
        for (int s = 0; s < 6; s++) {
            int t3 = s >> 1;
            int co = ((s & 1) << 6) + kq * 16;
            __half2 a0, a1, a2, a3;
            GBLEND(t3, co, a0, a1, a2, a3);
            uint4 hb = { u32of(a0), u32of(a1), u32of(a2), u32of(a3) };
            f16x8 bf = __builtin_bit_cast(f16x8, hb);
#pragma unroll
            for (int os = 0; os < 4; os++)
                acc[os] = __builtin_amdgcn_mfma_f32_16x16x32_f16(Wf[(s * 4 + os) * 64 + lane], bf, acc[os], 0, 0, 0);
        }
    } else {
#pragma unroll
        for (int s = 0; s < 6; s++) {
            int t3 = s >> 1;
            int co = ((s & 1) << 6) + kq * 16;
            __half2 a0, a1, a2, a3;
            GBLEND(t3, co, a0, a1, a2, a3);
            int idx = m * 96 + t3 * 32 + p;
            unsigned msk = *reinterpret_cast<const unsigned*>(smem8 + L_MSK + idx * 4);
            uchar4 cr = *reinterpret_cast<const uchar4*>(smem8 + L_CRD + idx * 4);
            if (__any(msk != 0)) {
                int cog = ((s & 1) << 5) + kq * 8;
                if (msk & 1u) {
                    int gx = (pbase + (int)cr.x * Wn + (int)cr.y) * 64;
                    uint4 u = *reinterpret_cast<const uint4*>(A16 + gx + cog);
                    a0 = __hfma2(bc2(u.x), wh[t3][0], a0); a1 = __hfma2(bc2(u.y), wh[t3][0], a1);
                    a2 = __hfma2(bc2(u.z), wh[t3][0], a2); a3 = __hfma2(bc2(u.w), wh[t3][0], a3); }
                if (msk & 2u) {
                    int gx = (pbase + (int)cr.x * Wn + (int)cr.w) * 64;
                    uint4 u = *reinterpret_cast<const uint4*>(A16 + gx + cog);
                    a0 = __hfma2(bc2(u.x), wh[t3][1], a0); a1 = __hfma2(bc2(u.y), wh[t3][1], a1);
                    a2 = __hfma2(bc2(u.z), wh[t3][1], a2); a3 = __hfma2(bc2(u.w), wh[t3][1], a3); }
                if (msk & 4u) {
                    int gx = (pbase + (int)cr.z * Wn + (int)cr.y) * 64;
                    uint4 u = *reinterpret_cast<const uint4*>(A16 + gx + cog);
                    a0 = __hfma2(bc2(u.x), wh[t3][2], a0); a1 = __hfma2(bc2(u.y), wh[t3][2], a1);
                    a2 = __hfma2(bc2(u.z), wh[t3][2], a2); a3 = __hfma2(bc2(u.w), wh[t3][2], a3); }
                if (msk & 8u) {
                    int gx = (pbase + (int)cr.z * Wn + (int)cr.w) * 64;
                    uint4 u = *reinterpret_cast<const uint4*>(A16 + gx + cog);
                    a0 = __hfma2(bc2(u.x), wh[t3][3], a0); a1 = __hfma2(bc2(u.y), wh[t3][3], a1);
                    a2 = __hfma2(bc2(u.z), wh[t3][3], a2); a3 = __hfma2(bc2(u.w), wh[t3][3], a3); }
            }
            uint4 hb = { u32of(a0), u32of(a1), u32of(a2), u32of(a3) };
            f16x8 bf = __builtin_bit_cast(f16x8, hb);
#pragma unroll
            for (int os = 0; os < 4; os++)
                acc[os] = __builtin_amdgcn_mfma_f32_16x16x32_f16(Wf[(s * 4 + os) * 64 + lane], bf, acc[os], 0, 0, 0);
        }
    }
#undef GBLEND

    // ---- sigma + exchange: EX f32[2][32][68] transposed, b128 ----
    const float* __restrict__ bias = m ? br : bc;
    float sg[4][4];
#pragma unroll
    for (int os = 0; os < 4; os++) {
        float4 bq = *reinterpret_cast<const float4*>(bias + os * 16 + kq * 4);
        const float* bqp = reinterpret_cast<const float*>(&bq);
#pragma unroll
        for (int rg = 0; rg < 4; rg++) sg[os][rg] = sigm(acc[os][rg] + bqp[rg]);
    }
    __syncthreads();
    float* EXf = reinterpret_cast<float*>(smem8);
#pragma unroll
    for (int os = 0; os < 4; os++) {
        float4 v = { sg[os][0], sg[os][1], sg[os][2], sg[os][3] };
        *reinterpret_cast<float4*>(&EXf[m * 2176 + p * 68 + os * 16 + kq * 4]) = v;
    }
    __syncthreads();

    // ---- epilogue ----
    int p2 = tid & 31, og = tid >> 5;
    int o0 = og * 8;
    size_t pix = ((size_t)b * Hn + h) * Wn + (w0 + p2);
    uint4 ua = *reinterpret_cast<const uint4*>(A16 + pix * 64 + o0);
    const __half* ap = reinterpret_cast<const __half*>(&ua);
    const __half* __restrict__ Ah16 = (const __half*)(ws8 + OFF_PRE_HIGH);
    uint4 uh = *reinterpret_cast<const uint4*>(Ah16 + pix * 64 + o0);
    const __half* hp = reinterpret_cast<const __half*>(&uh);
    float4 ec0 = *reinterpret_cast<const float4*>(&EXf[p2 * 68 + o0]);
    float4 ec1 = *reinterpret_cast<const float4*>(&EXf[p2 * 68 + o0 + 4]);
    float4 er0 = *reinterpret_cast<const float4*>(&EXf[2176 + p2 * 68 + o0]);
    float4 er1 = *reinterpret_cast<const float4*>(&EXf[2176 + p2 * 68 + o0 + 4]);
    const float* ecp = reinterpret_cast<const float*>(&ec0);
    const float* erp = reinterpret_cast<const float*>(&er0);
    const float* ecq = reinterpret_cast<const float*>(&ec1);
    const float* erq = reinterpret_cast<const float*>(&er1);
    size_t chbase = ((size_t)b * 64 + o0) * HWn + (size_t)h * Wn + (w0 + p2);
#pragma unroll
    for (int j = 0; j < 4; j++) {
        float av = __half2float(ap[j]);
        float hv = __half2float(hp[j]);
        out[chbase + (size_t)j * HWn] = 2.f * av + (ecp[j] + erp[j]) * hv;
    }
#pragma unroll
    for (int j = 0; j < 4; j++) {
        float av = __half2float(ap[4 + j]);
        float hv = __half2float(hp[4 + j]);
        out[chbase + (size_t)(4 + j) * HWn] = 2.f * av + (ecq[j] + erq[j]) * hv;
    }
}

extern "C" void kernel_launch(void* const* d_in, const int* in_sizes, int n_in,
                              void* d_out, int out_size, void* d_ws, size_t ws_size,
                              hipStream_t stream)
{
    const float* a_low  = (const float*)d_in[0];
    const float* a_high = (const float*)d_in[1];
    const float* pre_w1 = (const float*)d_in[2];
    const float* pre_b1 = (const float*)d_in[3];
    const float* pre_w2 = (const float*)d_in[4];
    const float* pre_b2 = (const float*)d_in[5];
    const float* offc_w = (const float*)d_in[6];
    const float* offc_b = (const float*)d_in[7];
    const float* wc     = (const float*)d_in[8];
    const float* bc     = (const float*)d_in[9];
    const float* offr_w = (const float*)d_in[10];
    const float* offr_b = (const float*)d_in[11];
    const float* wr     = (const float*)d_in[12];
    const float* br     = (const float*)d_in[13];
    float* out = (float*)d_out;
    char* ws8  = (char*)d_ws;

    hipLaunchKernelGGL(k_repack, dim3(128), dim3(256), 0, stream,
                       pre_w1, pre_w2, pre_b1, pre_b2, offc_w, offr_w, wc, wr, ws8);
    hipLaunchKernelGGL(k_pre, dim3(2048), dim3(256), 0, stream,
                       a_low, a_high, ws8);
    hipLaunchKernelGGL(k_om2, dim3(2048), dim3(256), 0, stream,
                       offc_b, offr_b, ws8);
    hipLaunchKernelGGL(k_dfuse, dim3(8192), dim3(256), 0, stream,
                       bc, br, out, ws8);
}

// Round 19
// 144.710 us; speedup vs baseline: 1.3191x; 1.3191x over previous
//
#include <hip/hip_runtime.h>
#include <hip/hip_fp16.h>
#include <cmath>

// Problem dims: B=4, C=64, H=W=256, k=3
namespace {
constexpr int Bn = 4, Cn = 64, Hn = 256, Wn = 256;
constexpr int HWn = Hn * Wn;              // 65536
// ws layout, BYTE offsets:
constexpr size_t OFF_PRE_LOW  = 0;          // a_low pre, NHWC f16, 33554432 B
constexpr size_t OFF_PRE_HIGH = 33554432;   // a_high pre, NHWC f16 (epilogue-only reader)
constexpr size_t OFF_OM_COL   = 67108864;   // om col (B,9,H,W) f16, 4718592 B
constexpr size_t OFF_OM_ROW   = 71827456;   // om row f16
constexpr size_t OFF_WOF16    = 85999616;   // offset-conv weights c-paired half2: [md][c2][k][9]
constexpr size_t OFF_WPACK    = 86013440;   // deform MFMA A-frag f16, 2 modes * 12288 halves
constexpr size_t OFF_WPRE     = 86062592;   // composed W2*W1 MFMA A-frag f16, 4096 halves
constexpr size_t OFF_BEFF     = 86070784;   // composed bias, 64 f32
// total ~86.1 MB. d_out is not used as scratch.

// k_dfuse LDS layout (bytes) — below 32KB for 5 blocks/CU:
constexpr int L_WIN  = 0;       // window: 180 px (5 rows x 36 cols) x 144 B
constexpr int L_MOFF = 25920;   // ushort4[192] window byte-offsets per (m,tap,p)
constexpr int L_MW   = 27456;   // __half[192][4] bilinear weights
constexpr int L_CRD  = 28992;   // uchar4[192] clamped corner coords (y0,x0,y1,x1)
constexpr int L_MSK  = 29760;   // uint[192] OOW corner mask (slow path only)
constexpr int L_ZL   = 30528;   // 144 B zero line
constexpr int L_TOT  = 30672;
// EX overlay f32[2][32][68] = 17408 B aliases window after gather barrier
}

typedef _Float16 f16x8 __attribute__((ext_vector_type(8)));
typedef float f32x4 __attribute__((ext_vector_type(4)));

__device__ __forceinline__ float sigm(float x) { return 1.f / (1.f + __expf(-x)); }
__device__ __forceinline__ __half2 bc2(unsigned u) { return __builtin_bit_cast(__half2, u); }
__device__ __forceinline__ unsigned u32of(__half2 h) { return __builtin_bit_cast(unsigned, h); }

// ---------------- weight repack + W2*W1 composition (tiny) ----------------
__global__ void k_repack(const float* __restrict__ pw1, const float* __restrict__ pw2,
                         const float* __restrict__ b1,  const float* __restrict__ b2,
                         const float* __restrict__ owc, const float* __restrict__ owr,
                         const float* __restrict__ wc,  const float* __restrict__ wr,
                         char* __restrict__ ws8)
{
    unsigned* Wo2  = (unsigned*)(ws8 + OFF_WOF16);
    __half*   Wp   = (__half*)(ws8 + OFF_WPACK);
    __half*   Wpre = (__half*)(ws8 + OFF_WPRE);
    float*    Beff = (float*)(ws8 + OFF_BEFF);
    int t = blockIdx.x * 256 + threadIdx.x;
    int stride = gridDim.x * 256;
    // offset-conv weights channel-paired half2: Wo2[md*864 + c2*27 + k*9 + d]
    for (int i = t; i < 1728; i += stride) {
        int md = i >= 864;
        int rem = i - md * 864;
        int c2 = rem / 27, kd = rem - c2 * 27;
        int k = kd / 9, d = kd - k * 9;
        const float* src = md ? owr : owc;
        float lo = src[d * 192 + (2 * c2) * 3 + k];
        float hi = src[d * 192 + (2 * c2 + 1) * 3 + k];
        Wo2[i] = u32of(__floats2half2_rn(lo, hi));
    }
    // deform MFMA A-frag pack (f16)
    for (int i = t; i < 24576; i += stride) {
        int m = i >= 12288;
        int rem = i - m * 12288;
        int e = rem & 7, l = (rem >> 3) & 63, os = (rem >> 9) & 3, s = rem >> 11;
        int kk = 32 * s + (l >> 4) * 8 + e;
        int o = os * 16 + (l & 15);
        int c = kk & 63, tap = kk >> 6;
        const float* src = m ? wr : wc;
        Wp[i] = __float2half(src[o * 192 + c * 3 + tap]);
    }
    // composed preprocess weight + bias
    for (int i = t; i < 4096; i += stride) {
        int e = i & 7, l = (i >> 3) & 63, os = (i >> 9) & 3, s = i >> 11;
        int o = os * 16 + (l & 15);
        int c = 32 * s + (l >> 4) * 8 + e;
        float a = 0.f;
        for (int j = 0; j < 32; j++) a += pw2[o * 32 + j] * pw1[j * 64 + c];
        Wpre[i] = __float2half(a);
    }
    for (int i = t; i < 64; i += stride) {
        float a = b2[i];
        for (int j = 0; j < 32; j++) a += pw2[i * 32 + j] * b1[j];
        Beff[i] = a;
    }
}

// ---------------- preprocess via composed MFMA GEMM (NHWC-only outputs) ----------------
__global__ __launch_bounds__(256) void k_pre(const float* __restrict__ alow,
                                             const float* __restrict__ ahigh,
                                             char* __restrict__ ws8)
{
    __shared__ __align__(16) char XSb[32768];   // XS[px 256][c 64] f16, swizzled
    int bid = blockIdx.x;                // [0, 2048)
    int tensor = bid >> 10;
    int r = bid & 1023;                  // b*256 + h
    const float* __restrict__ x = (tensor ? ahigh : alow) + (size_t)r * Wn
                                  + (size_t)(r >> 8) * (Cn - 1) * HWn;
    int tid = threadIdx.x;

#pragma unroll
    for (int it = 0; it < 4; it++) {
        int job = tid + it * 256;
        int c4 = job >> 6, pxg = job & 63;
        int c0 = c4 * 4;
        float4 f0 = *reinterpret_cast<const float4*>(x + (size_t)(c0 + 0) * HWn + pxg * 4);
        float4 f1 = *reinterpret_cast<const float4*>(x + (size_t)(c0 + 1) * HWn + pxg * 4);
        float4 f2 = *reinterpret_cast<const float4*>(x + (size_t)(c0 + 2) * HWn + pxg * 4);
        float4 f3 = *reinterpret_cast<const float4*>(x + (size_t)(c0 + 3) * HWn + pxg * 4);
        const float* p0 = reinterpret_cast<const float*>(&f0);
        const float* p1 = reinterpret_cast<const float*>(&f1);
        const float* p2 = reinterpret_cast<const float*>(&f2);
        const float* p3 = reinterpret_cast<const float*>(&f3);
        int u = c4 >> 1, hf = c4 & 1;
#pragma unroll
        for (int i = 0; i < 4; i++) {
            int px = pxg * 4 + i;
            uint2 v;
            v.x = u32of(__float22half2_rn({p0[i], p1[i]}));
            v.y = u32of(__float22half2_rn({p2[i], p3[i]}));
            *reinterpret_cast<uint2*>(XSb + px * 128 + ((u ^ (px & 7)) * 16) + hf * 8) = v;
        }
    }
    __syncthreads();

    int wv = tid >> 6, lane = tid & 63;
    int kq = lane >> 4, n = lane & 15;
    const f16x8* __restrict__ Wf = (const f16x8*)(ws8 + OFF_WPRE);
    const float* __restrict__ beff = (const float*)(ws8 + OFF_BEFF);
    f16x8 af[8];
#pragma unroll
    for (int i = 0; i < 8; i++) af[i] = Wf[i * 64 + lane];
    f32x4 zero = {0.f, 0.f, 0.f, 0.f};
    f32x4 acc[16];
#pragma unroll
    for (int i = 0; i < 16; i++) acc[i] = zero;
#pragma unroll
    for (int s = 0; s < 2; s++) {
#pragma unroll
        for (int pt = 0; pt < 4; pt++) {
            int px = wv * 64 + pt * 16 + n;
            int u = (4 * s + kq) ^ (px & 7);
            f16x8 bf = *reinterpret_cast<const f16x8*>(XSb + px * 128 + u * 16);
#pragma unroll
            for (int os = 0; os < 4; os++)
                acc[os * 4 + pt] = __builtin_amdgcn_mfma_f32_16x16x32_f16(
                    af[s * 4 + os], bf, acc[os * 4 + pt], 0, 0, 0);
        }
    }
#pragma unroll
    for (int os = 0; os < 4; os++) {
        float4 bq = *reinterpret_cast<const float4*>(beff + os * 16 + kq * 4);
        const float* bqp = reinterpret_cast<const float*>(&bq);
#pragma unroll
        for (int pt = 0; pt < 4; pt++)
#pragma unroll
            for (int rg = 0; rg < 4; rg++) acc[os * 4 + pt][rg] += bqp[rg];
    }

    __half* __restrict__ outp = (__half*)(ws8 + (tensor ? OFF_PRE_HIGH : OFF_PRE_LOW))
                                + (size_t)r * 16384;
#pragma unroll
    for (int os = 0; os < 4; os++)
#pragma unroll
        for (int pt = 0; pt < 4; pt++) {
            int px = wv * 64 + pt * 16 + n;
            uint2 v;
            v.x = u32of(__float22half2_rn({acc[os * 4 + pt][0], acc[os * 4 + pt][1]}));
            v.y = u32of(__float22half2_rn({acc[os * 4 + pt][2], acc[os * 4 + pt][3]}));
            *reinterpret_cast<uint2*>(outp + (size_t)px * 64 + os * 16 + kq * 4) = v;
        }
}

// ---------------- offset convs from NHWC: thread = (pixel, mode) ----------------
// XCD-banded mapping: each XCD owns a contiguous 128-row band (4MB = L2) for
// both modes, so row h is HBM-fetched once and L2-reused by h+-1 neighbors.
__global__ __launch_bounds__(256) void k_om2(const float* __restrict__ ocb,
                                             const float* __restrict__ orb,
                                             char* __restrict__ ws8)
{
    int bid = blockIdx.x;                 // [0, 2048), bijective remap:
    int xcd = bid & 7;
    int i = bid >> 3;                     // [0, 256)
    int md = i >> 7;                      // 0..1
    int r = xcd * 128 + (i & 127);        // [0, 1024) contiguous band per XCD
    int h = r & 255;
    int w = threadIdx.x;
    const __half* __restrict__ A = (const __half*)(ws8 + OFF_PRE_LOW);
    const uint4* __restrict__ pc = reinterpret_cast<const uint4*>(A + ((size_t)r * 256 + w) * 64);
    bool v0, v2;
    int o0, o2;
    if (md == 0) { v0 = (h > 0);  v2 = (h < Hn - 1); o0 = -2048; o2 = 2048; }
    else         { v0 = (w > 0);  v2 = (w < Wn - 1); o0 = -8;    o2 = 8; }
    const uint4* p0 = pc + (v0 ? o0 : 0);
    const uint4* p2 = pc + (v2 ? o2 : 0);
    const unsigned* __restrict__ Wt = (const unsigned*)(ws8 + OFF_WOF16) + md * 864;

    const __half2 z = __float2half2_rn(0.f);
    uint4 z4 = {0u, 0u, 0u, 0u};
    __half2 acc[9];
#pragma unroll
    for (int d = 0; d < 9; d++) acc[d] = z;

#pragma unroll 2
    for (int u = 0; u < 8; u++) {
        uint4 x0 = p0[u]; if (!v0) x0 = z4;
        uint4 x1 = pc[u];
        uint4 x2 = p2[u]; if (!v2) x2 = z4;
        const unsigned* xp0 = reinterpret_cast<const unsigned*>(&x0);
        const unsigned* xp1 = reinterpret_cast<const unsigned*>(&x1);
        const unsigned* xp2 = reinterpret_cast<const unsigned*>(&x2);
#pragma unroll
        for (int j = 0; j < 4; j++) {
            int c2 = u * 4 + j;
            const unsigned* wb = Wt + c2 * 27;
            __half2 a0 = bc2(xp0[j]), a1 = bc2(xp1[j]), a2 = bc2(xp2[j]);
#pragma unroll
            for (int d = 0; d < 9; d++)
                acc[d] = __hfma2(bc2(wb[d]), a0,
                          __hfma2(bc2(wb[9 + d]), a1,
                           __hfma2(bc2(wb[18 + d]), a2, acc[d])));
        }
    }

    const float* __restrict__ bias = md ? orb : ocb;
    __half* __restrict__ om = (__half*)(ws8 + (md ? OFF_OM_ROW : OFF_OM_COL));
    size_t ob = ((size_t)(r >> 8) * 9) * HWn + (size_t)h * Wn + w;
#pragma unroll
    for (int d = 0; d < 9; d++) {
        float v = __low2float(acc[d]) + __high2float(acc[d]) + bias[d];
        om[ob + (size_t)d * HWn] = __float2half(v);
    }
}

// ---------------- fused deformable conv: LDS-window gather, 5 blocks/CU ----------------
__global__ __launch_bounds__(256, 5) void k_dfuse(const float* __restrict__ bc,
                                                  const float* __restrict__ br,
                                                  float* __restrict__ out,
                                                  char* __restrict__ ws8)
{
    __shared__ __align__(16) char smem8[L_TOT];

    const __half* __restrict__ A16 = (const __half*)(ws8 + OFF_PRE_LOW);

    int bid = blockIdx.x;                 // 8192 blocks, 8192 % 8 == 0 (bijective)
    int blk = (bid & 7) * 1024 + (bid >> 3);
    int wt = blk & 7, bh = blk >> 3, h = bh & 255, b = bh >> 8;
    int w0 = wt * 32;
    int tid = threadIdx.x;
    int pbase = b * HWn;

    // ---- stage 5x36 window (all threads; coalesced 16B chunks) ----
    {
        int ylo = h - 2, xlo = w0 - 2;
#pragma unroll
        for (int i = 0; i < 6; i++) {
            int idx = tid + i * 256;
            if (idx < 1440) {
                int pixw = idx >> 3, ch = idx & 7;
                int r = pixw / 36;
                int xi = pixw - r * 36;
                int y = min(max(ylo + r, 0), Hn - 1);
                int x = min(max(xlo + xi, 0), Wn - 1);
                size_t src = ((size_t)pbase + y * Wn + x) * 64 + ch * 8;
                *reinterpret_cast<uint4*>(smem8 + L_WIN + pixw * 144 + ch * 16) =
                    *reinterpret_cast<const uint4*>(A16 + src);
            }
        }
    }
    if (tid >= 192 && tid < 201) {
        uint4 z4 = {0u, 0u, 0u, 0u};
        *reinterpret_cast<uint4*>(smem8 + L_ZL + (tid - 192) * 16) = z4;
    }

    // ---- decode (threads 0..191) ----
    int myMsk = 0;
    if (tid < 192) {
        int m = tid >= 96 ? 1 : 0;
        int jj = tid - m * 96;            // tap*32 + p
        int p = jj & 31, tap = jj >> 5;
        int w = w0 + p;
        const __half* __restrict__ om = (const __half*)(ws8 + (m ? OFF_OM_ROW : OFF_OM_COL));
        size_t ob = ((size_t)b * 9 * Hn + h) * Wn + w;
        float dy = __half2float(om[ob + (size_t)tap * HWn]);
        float dx = __half2float(om[ob + (size_t)(3 + tap) * HWn]);
        float mm = __half2float(om[ob + (size_t)(6 + tap) * HWn]);
        float mask = sigm(mm);
        float py = dy + (float)h + (m ? 0.f : (float)(tap - 1));
        float px = dx + (float)w + (m ? (float)(tap - 1) : 0.f);
        float fy = floorf(py), fx = floorf(px);
        float ty = py - fy, tx = px - fx;
        int y0 = (int)fy, x0 = (int)fx;
        int y1 = y0 + 1, x1 = x0 + 1;
        float vy0 = ((unsigned)y0 < (unsigned)Hn) ? 1.f : 0.f;
        float vy1 = ((unsigned)y1 < (unsigned)Hn) ? 1.f : 0.f;
        float vx0 = ((unsigned)x0 < (unsigned)Wn) ? 1.f : 0.f;
        float vx1 = ((unsigned)x1 < (unsigned)Wn) ? 1.f : 0.f;
        int y0c = min(max(y0, 0), Hn - 1), y1c = min(max(y1, 0), Hn - 1);
        int x0c = min(max(x0, 0), Wn - 1), x1c = min(max(x1, 0), Wn - 1);
        float ry = 1.f - ty, rx = 1.f - tx;
        float w00 = ry * rx * mask * vy0 * vx0;
        float w01 = ry * tx * mask * vy0 * vx1;
        float w10 = ty * rx * mask * vy1 * vx0;
        float w11 = ty * tx * mask * vy1 * vx1;
        int yw0 = y0c - (h - 2), yw1 = y1c - (h - 2);
        int xw0 = x0c - (w0 - 2), xw1 = x1c - (w0 - 2);
        bool i00 = ((unsigned)yw0 < 5u) && ((unsigned)xw0 < 36u);
        bool i01 = ((unsigned)yw0 < 5u) && ((unsigned)xw1 < 36u);
        bool i10 = ((unsigned)yw1 < 5u) && ((unsigned)xw0 < 36u);
        bool i11 = ((unsigned)yw1 < 5u) && ((unsigned)xw1 < 36u);
        ushort4 offs;
        offs.x = i00 ? (ushort)((yw0 * 36 + xw0) * 144) : (ushort)L_ZL;
        offs.y = i01 ? (ushort)((yw0 * 36 + xw1) * 144) : (ushort)L_ZL;
        offs.z = i10 ? (ushort)((yw1 * 36 + xw0) * 144) : (ushort)L_ZL;
        offs.w = i11 ? (ushort)((yw1 * 36 + xw1) * 144) : (ushort)L_ZL;
        *reinterpret_cast<ushort4*>(smem8 + L_MOFF + tid * 8) = offs;
        __half* mw = reinterpret_cast<__half*>(smem8 + L_MW + tid * 8);
        mw[0] = __float2half(w00); mw[1] = __float2half(w01);
        mw[2] = __float2half(w10); mw[3] = __float2half(w11);
        uchar4 cr = { (unsigned char)y0c, (unsigned char)x0c,
                      (unsigned char)y1c, (unsigned char)x1c };
        *reinterpret_cast<uchar4*>(smem8 + L_CRD + tid * 4) = cr;
        myMsk = (i00 ? 0 : 1) | (i01 ? 0 : 2) | (i10 ? 0 : 4) | (i11 ? 0 : 8);
        *reinterpret_cast<unsigned*>(smem8 + L_MSK + tid * 4) = (unsigned)myMsk;
    }
    int anyOOW = __syncthreads_or(myMsk);

    // ---- gather (from LDS) + GEMM ----
    int wv = tid >> 6, lane = tid & 63;
    int m = wv >> 1, pg = wv & 1;
    int n = lane & 15, kq = lane >> 4;
    int p = pg * 16 + n;
    const f16x8* __restrict__ Wf = (const f16x8*)(ws8 + OFF_WPACK + (size_t)m * 24576);

    ushort4 offs[3];
    __half2 wh[3][4];
#pragma unroll
    for (int t3 = 0; t3 < 3; t3++) {
        int idx = m * 96 + t3 * 32 + p;
        offs[t3] = *reinterpret_cast<const ushort4*>(smem8 + L_MOFF + idx * 8);
        uint2 wr_ = *reinterpret_cast<const uint2*>(smem8 + L_MW + idx * 8);
        __half2 wa = bc2(wr_.x), wb = bc2(wr_.y);
        wh[t3][0] = __half2half2(__low2half(wa));
        wh[t3][1] = __half2half2(__high2half(wa));
        wh[t3][2] = __half2half2(__low2half(wb));
        wh[t3][3] = __half2half2(__high2half(wb));
    }

    f32x4 zero = {0.f, 0.f, 0.f, 0.f};
    f32x4 acc[4] = {zero, zero, zero, zero};

#define GBLEND(T, CO, A0, A1, A2, A3)                                            \
    {                                                                            \
        uint4 u0 = *reinterpret_cast<const uint4*>(smem8 + (int)offs[T].x + (CO)); \
        uint4 u1 = *reinterpret_cast<const uint4*>(smem8 + (int)offs[T].y + (CO)); \
        uint4 u2 = *reinterpret_cast<const uint4*>(smem8 + (int)offs[T].z + (CO)); \
        uint4 u3 = *reinterpret_cast<const uint4*>(smem8 + (int)offs[T].w + (CO)); \
        A0 = __hmul2(bc2(u0.x), wh[T][0]); A1 = __hmul2(bc2(u0.y), wh[T][0]);    \
        A2 = __hmul2(bc2(u0.z), wh[T][0]); A3 = __hmul2(bc2(u0.w), wh[T][0]);    \
        A0 = __hfma2(bc2(u1.x), wh[T][1], A0); A1 = __hfma2(bc2(u1.y), wh[T][1], A1); \
        A2 = __hfma2(bc2(u1.z), wh[T][1], A2); A3 = __hfma2(bc2(u1.w), wh[T][1], A3); \
        A0 = __hfma2(bc2(u2.x), wh[T][2], A0); A1 = __hfma2(bc2(u2.y), wh[T][2], A1); \
        A2 = __hfma2(bc2(u2.z), wh[T][2], A2); A3 = __hfma2(bc2(u2.w), wh[T][2], A3); \
        A0 = __hfma2(bc2(u3.x), wh[T][3], A0); A1 = __hfma2(bc2(u3.y), wh[T][3], A1); \
        A2 = __hfma2(bc2(u3.z), wh[T][3], A2); A3 = __hfma2(bc2(u3.w), wh[T][3], A3); \
    }

    if (!anyOOW) {
#pragma unroll
        for (int s = 0; s < 6; s++) {
            int t3 = s >> 1;
            int co = ((s & 1) << 6) + kq * 16;
            __half2 a0, a1, a2, a3;
            GBLEND(t3, co, a0, a1, a2, a3);
            uint4 hb = { u32of(a0), u32of(a1), u32of(a2), u32of(a3) };
            f16x8 bf = __builtin_bit_cast(f16x8, hb);
#pragma unroll
            for (int os = 0; os < 4; os++)
                acc[os] = __builtin_amdgcn_mfma_f32_16x16x32_f16(Wf[(s * 4 + os) * 64 + lane], bf, acc[os], 0, 0, 0);
        }
    } else {
#pragma unroll
        for (int s = 0; s < 6; s++) {
            int t3 = s >> 1;
            int co = ((s & 1) << 6) + kq * 16;
            __half2 a0, a1, a2, a3;
            GBLEND(t3, co, a0, a1, a2, a3);
            int idx = m * 96 + t3 * 32 + p;
            unsigned msk = *reinterpret_cast<const unsigned*>(smem8 + L_MSK + idx * 4);
            uchar4 cr = *reinterpret_cast<const uchar4*>(smem8 + L_CRD + idx * 4);
            if (__any(msk != 0)) {
                int cog = ((s & 1) << 5) + kq * 8;
                if (msk & 1u) {
                    int gx = (pbase + (int)cr.x * Wn + (int)cr.y) * 64;
                    uint4 u = *reinterpret_cast<const uint4*>(A16 + gx + cog);
                    a0 = __hfma2(bc2(u.x), wh[t3][0], a0); a1 = __hfma2(bc2(u.y), wh[t3][0], a1);
                    a2 = __hfma2(bc2(u.z), wh[t3][0], a2); a3 = __hfma2(bc2(u.w), wh[t3][0], a3); }
                if (msk & 2u) {
                    int gx = (pbase + (int)cr.x * Wn + (int)cr.w) * 64;
                    uint4 u = *reinterpret_cast<const uint4*>(A16 + gx + cog);
                    a0 = __hfma2(bc2(u.x), wh[t3][1], a0); a1 = __hfma2(bc2(u.y), wh[t3][1], a1);
                    a2 = __hfma2(bc2(u.z), wh[t3][1], a2); a3 = __hfma2(bc2(u.w), wh[t3][1], a3); }
                if (msk & 4u) {
                    int gx = (pbase + (int)cr.z * Wn + (int)cr.y) * 64;
                    uint4 u = *reinterpret_cast<const uint4*>(A16 + gx + cog);
                    a0 = __hfma2(bc2(u.x), wh[t3][2], a0); a1 = __hfma2(bc2(u.y), wh[t3][2], a1);
                    a2 = __hfma2(bc2(u.z), wh[t3][2], a2); a3 = __hfma2(bc2(u.w), wh[t3][2], a3); }
                if (msk & 8u) {
                    int gx = (pbase + (int)cr.z * Wn + (int)cr.w) * 64;
                    uint4 u = *reinterpret_cast<const uint4*>(A16 + gx + cog);
                    a0 = __hfma2(bc2(u.x), wh[t3][3], a0); a1 = __hfma2(bc2(u.y), wh[t3][3], a1);
                    a2 = __hfma2(bc2(u.z), wh[t3][3], a2); a3 = __hfma2(bc2(u.w), wh[t3][3], a3); }
            }
            uint4 hb = { u32of(a0), u32of(a1), u32of(a2), u32of(a3) };
            f16x8 bf = __builtin_bit_cast(f16x8, hb);
#pragma unroll
            for (int os = 0; os < 4; os++)
                acc[os] = __builtin_amdgcn_mfma_f32_16x16x32_f16(Wf[(s * 4 + os) * 64 + lane], bf, acc[os], 0, 0, 0);
        }
    }
#undef GBLEND

    // ---- sigma + exchange: EX f32[2][32][68] transposed, b128 ----
    const float* __restrict__ bias = m ? br : bc;
    float sg[4][4];
#pragma unroll
    for (int os = 0; os < 4; os++) {
        float4 bq = *reinterpret_cast<const float4*>(bias + os * 16 + kq * 4);
        const float* bqp = reinterpret_cast<const float*>(&bq);
#pragma unroll
        for (int rg = 0; rg < 4; rg++) sg[os][rg] = sigm(acc[os][rg] + bqp[rg]);
    }
    __syncthreads();
    float* EXf = reinterpret_cast<float*>(smem8);
#pragma unroll
    for (int os = 0; os < 4; os++) {
        float4 v = { sg[os][0], sg[os][1], sg[os][2], sg[os][3] };
        *reinterpret_cast<float4*>(&EXf[m * 2176 + p * 68 + os * 16 + kq * 4]) = v;
    }
    __syncthreads();

    // ---- epilogue ----
    int p2 = tid & 31, og = tid >> 5;
    int o0 = og * 8;
    size_t pix = ((size_t)b * Hn + h) * Wn + (w0 + p2);
    uint4 ua = *reinterpret_cast<const uint4*>(A16 + pix * 64 + o0);
    const __half* ap = reinterpret_cast<const __half*>(&ua);
    const __half* __restrict__ Ah16 = (const __half*)(ws8 + OFF_PRE_HIGH);
    uint4 uh = *reinterpret_cast<const uint4*>(Ah16 + pix * 64 + o0);
    const __half* hp = reinterpret_cast<const __half*>(&uh);
    float4 ec0 = *reinterpret_cast<const float4*>(&EXf[p2 * 68 + o0]);
    float4 ec1 = *reinterpret_cast<const float4*>(&EXf[p2 * 68 + o0 + 4]);
    float4 er0 = *reinterpret_cast<const float4*>(&EXf[2176 + p2 * 68 + o0]);
    float4 er1 = *reinterpret_cast<const float4*>(&EXf[2176 + p2 * 68 + o0 + 4]);
    const float* ecp = reinterpret_cast<const float*>(&ec0);
    const float* erp = reinterpret_cast<const float*>(&er0);
    const float* ecq = reinterpret_cast<const float*>(&ec1);
    const float* erq = reinterpret_cast<const float*>(&er1);
    size_t chbase = ((size_t)b * 64 + o0) * HWn + (size_t)h * Wn + (w0 + p2);
#pragma unroll
    for (int j = 0; j < 4; j++) {
        float av = __half2float(ap[j]);
        float hv = __half2float(hp[j]);
        out[chbase + (size_t)j * HWn] = 2.f * av + (ecp[j] + erp[j]) * hv;
    }
#pragma unroll
    for (int j = 0; j < 4; j++) {
        float av = __half2float(ap[4 + j]);
        float hv = __half2float(hp[4 + j]);
        out[chbase + (size_t)(4 + j) * HWn] = 2.f * av + (ecq[j] + erq[j]) * hv;
    }
}

extern "C" void kernel_launch(void* const* d_in, const int* in_sizes, int n_in,
                              void* d_out, int out_size, void* d_ws, size_t ws_size,
                              hipStream_t stream)
{
    const float* a_low  = (const float*)d_in[0];
    const float* a_high = (const float*)d_in[1];
    const float* pre_w1 = (const float*)d_in[2];
    const float* pre_b1 = (const float*)d_in[3];
    const float* pre_w2 = (const float*)d_in[4];
    const float* pre_b2 = (const float*)d_in[5];
    const float* offc_w = (const float*)d_in[6];
    const float* offc_b = (const float*)d_in[7];
    const float* wc     = (const float*)d_in[8];
    const float* bc     = (const float*)d_in[9];
    const float* offr_w = (const float*)d_in[10];
    const float* offr_b = (const float*)d_in[11];
    const float* wr     = (const float*)d_in[12];
    const float* br     = (const float*)d_in[13];
    float* out = (float*)d_out;
    char* ws8  = (char*)d_ws;

    hipLaunchKernelGGL(k_repack, dim3(128), dim3(256), 0, stream,
                       pre_w1, pre_w2, pre_b1, pre_b2, offc_w, offr_w, wc, wr, ws8);
    hipLaunchKernelGGL(k_pre, dim3(2048), dim3(256), 0, stream,
                       a_low, a_high, ws8);
    hipLaunchKernelGGL(k_om2, dim3(2048), dim3(256), 0, stream,
                       offc_b, offr_b, ws8);
    hipLaunchKernelGGL(k_dfuse, dim3(8192), dim3(256), 0, stream,
                       bc, br, out, ws8);
}